// Round 4
// baseline (562.083 us; speedup 1.0000x reference)
//
#include <hip/hip_runtime.h>
#include <hip/hip_bf16.h>

typedef __hip_bfloat16 bf16;
typedef __attribute__((ext_vector_type(8))) __bf16 bf16x8;
typedef __attribute__((ext_vector_type(4))) float f32x4;

#define HW 16384

static __device__ __forceinline__ float b2f(bf16 v) { return __bfloat162float(v); }
static __device__ __forceinline__ bf16 f2b(float v) { return __float2bfloat16(v); }
static __device__ __forceinline__ float blo(unsigned int w) {
    return __uint_as_float(w << 16);
}
static __device__ __forceinline__ float bhi(unsigned int w) {
    return __uint_as_float(w & 0xffff0000u);
}
static __device__ __forceinline__ unsigned short f2bu(float v) {
    union { bf16 b; unsigned short u; } c; c.b = f2b(v); return c.u;
}
static __device__ __forceinline__ void stf(float* p, float v) { *p = v; }
static __device__ __forceinline__ void stf(bf16* p, float v)  { *p = f2b(v); }

static __device__ __forceinline__ void load8(const float* p, float* v) {
    const float4* q = (const float4*)p;
    float4 a = q[0], b = q[1];
    v[0] = a.x; v[1] = a.y; v[2] = a.z; v[3] = a.w;
    v[4] = b.x; v[5] = b.y; v[6] = b.z; v[7] = b.w;
}
static __device__ __forceinline__ void load8(const bf16* p, float* v) {
    uint4 u = *(const uint4*)p;
    v[0] = blo(u.x); v[1] = bhi(u.x); v[2] = blo(u.y); v[3] = bhi(u.y);
    v[4] = blo(u.z); v[5] = bhi(u.z); v[6] = blo(u.w); v[7] = bhi(u.w);
}

// ============ T0: transpose + cast  x[b][192][HW] f32 -> xT[b][HW][192] bf16
// 64k x 64n tile through padded LDS; conflict-free both phases.
__global__ __launch_bounds__(256) void transpose_cast(
    const float* __restrict__ x, bf16* __restrict__ xT)
{
    __shared__ float T[64][65];
    const int k0 = blockIdx.x * 64, n0 = blockIdx.y * 64, b = blockIdx.z;
    const float* xb = x + ((size_t)(b * 192 + k0) << 14) + n0;

    for (int s = threadIdx.x; s < 64 * 16; s += 256) {
        int k = s >> 4, n4 = (s & 15) * 4;
        float4 v = *(const float4*)(xb + ((size_t)k << 14) + n4);
        T[k][n4] = v.x; T[k][n4 + 1] = v.y; T[k][n4 + 2] = v.z; T[k][n4 + 3] = v.w;
    }
    __syncthreads();

    bf16* xo = xT + ((size_t)b << 14) * 192 + (size_t)n0 * 192 + k0;
    for (int s = threadIdx.x; s < 64 * 8; s += 256) {
        int n = s >> 3, k8 = (s & 7) * 8;
        union { unsigned short u[8]; uint4 v; } o;
#pragma unroll
        for (int j = 0; j < 8; j++) o.u[j] = f2bu(T[k8 + j][n]);
        *(uint4*)(xo + (size_t)n * 192 + k8) = o.v;
    }
}

// ============ K1/K7: GEMM  Y[b][m][n] = W[m][k] (f32) @ BT[b][n][k] (bf16)
// K = 192 fixed, fully LDS-resident; 64m x 128n block, 4 waves of 32x64.
// Both operands k-contiguous -> all b128, no transpose, no conflicts.
template <typename TY>
__global__ __launch_bounds__(256) void gemm_nk(
    const float* __restrict__ Wm, const bf16* __restrict__ Bt,
    TY* __restrict__ Y, int M, int N)
{
    const int mb = blockIdx.x, nb = blockIdx.y, b = blockIdx.z;
    const int m0 = mb * 64, n0 = nb * 128;
    TY* Yb = Y + (size_t)b * M * N;
    const bf16* Bb = Bt + ((size_t)b * N + n0) * 192;

    __shared__ __bf16 As[64][200];   // 400B rows -> 100dw ≡ 4 mod 32: 2-way
    __shared__ __bf16 Bs[128][200];

    const int tid = threadIdx.x;
    // stage A (f32 -> bf16): 64 rows x 24 slots of 8
    for (int s = tid; s < 64 * 24; s += 256) {
        int m = s / 24, kq = (s % 24) * 8;
        float v[8];
        load8(Wm + (size_t)(m0 + m) * 192 + kq, v);
        bf16x8 pk;
#pragma unroll
        for (int j = 0; j < 8; j++) pk[j] = (__bf16)v[j];
        *(bf16x8*)&As[m][kq] = pk;
    }
    // stage B (bf16 copy): 128 rows x 24 uint4 slots
    for (int s = tid; s < 128 * 24; s += 256) {
        int n = s / 24, kq = s % 24;
        *(uint4*)&Bs[n][kq * 8] = *(const uint4*)(Bb + (size_t)n * 192 + kq * 8);
    }
    __syncthreads();

    const int lane = tid & 63, wave = tid >> 6;
    const int wm = (wave & 1) * 32, wn = (wave >> 1) * 64;
    const int r16 = lane & 15, quad = lane >> 4;

    f32x4 acc[2][4];
#pragma unroll
    for (int i = 0; i < 2; i++)
#pragma unroll
        for (int f = 0; f < 4; f++) acc[i][f] = (f32x4){0.f, 0.f, 0.f, 0.f};

#pragma unroll
    for (int kc = 0; kc < 6; kc++) {
        const int kb = kc * 32 + quad * 8;
        bf16x8 a0 = *(const bf16x8*)&As[wm + r16][kb];
        bf16x8 a1 = *(const bf16x8*)&As[wm + 16 + r16][kb];
        bf16x8 b0 = *(const bf16x8*)&Bs[wn + r16][kb];
        bf16x8 b1 = *(const bf16x8*)&Bs[wn + 16 + r16][kb];
        bf16x8 b2 = *(const bf16x8*)&Bs[wn + 32 + r16][kb];
        bf16x8 b3 = *(const bf16x8*)&Bs[wn + 48 + r16][kb];
        acc[0][0] = __builtin_amdgcn_mfma_f32_16x16x32_bf16(a0, b0, acc[0][0], 0, 0, 0);
        acc[0][1] = __builtin_amdgcn_mfma_f32_16x16x32_bf16(a0, b1, acc[0][1], 0, 0, 0);
        acc[0][2] = __builtin_amdgcn_mfma_f32_16x16x32_bf16(a0, b2, acc[0][2], 0, 0, 0);
        acc[0][3] = __builtin_amdgcn_mfma_f32_16x16x32_bf16(a0, b3, acc[0][3], 0, 0, 0);
        acc[1][0] = __builtin_amdgcn_mfma_f32_16x16x32_bf16(a1, b0, acc[1][0], 0, 0, 0);
        acc[1][1] = __builtin_amdgcn_mfma_f32_16x16x32_bf16(a1, b1, acc[1][1], 0, 0, 0);
        acc[1][2] = __builtin_amdgcn_mfma_f32_16x16x32_bf16(a1, b2, acc[1][2], 0, 0, 0);
        acc[1][3] = __builtin_amdgcn_mfma_f32_16x16x32_bf16(a1, b3, acc[1][3], 0, 0, 0);
    }

    // C/D: col = lane&15, row = quad*4 + reg  [verified m89/m91]
#pragma unroll
    for (int i = 0; i < 2; i++)
#pragma unroll
        for (int f = 0; f < 4; f++) {
            int gr = m0 + wm + i * 16 + quad * 4;
            int gc = n0 + wn + f * 16 + r16;
#pragma unroll
            for (int r = 0; r < 4; r++)
                stf(Yb + (size_t)(gr + r) * N + gc, acc[i][f][r]);
        }
}

// ============ K2: depthwise 3x3, pad 1 — LDS-tiled, vectorized ==============
__global__ __launch_bounds__(256) void dwconv3x3(
    const bf16* __restrict__ in, const float* __restrict__ wdw,
    bf16* __restrict__ out)
{
    const int plane = blockIdx.x >> 2;          // b*576 + c
    const int ybase = (blockIdx.x & 3) << 5;    // 0,32,64,96
    const int c = plane % 576;
    const bf16* ip = in + ((size_t)plane << 14);

    __shared__ unsigned short Ls[34][128];

    for (int i = threadIdx.x; i < 34 * 16; i += 256) {
        int r = i >> 4, cx = i & 15;
        int y = ybase - 1 + r;
        uint4 v = make_uint4(0u, 0u, 0u, 0u);
        if (y >= 0 && y < 128) v = ((const uint4*)(ip + ((size_t)y << 7)))[cx];
        ((uint4*)Ls[r])[cx] = v;
    }

    float w[9];
#pragma unroll
    for (int i = 0; i < 9; i++) w[i] = wdw[c * 9 + i];

    __syncthreads();

    const int lr = threadIdx.x >> 3;
    const int c0 = (threadIdx.x & 7) << 4;

    float row[3][18];
#pragma unroll
    for (int r3 = 0; r3 < 3; r3++) {
        int rr = lr + r3;
        row[r3][0]  = c0 ? __uint_as_float((unsigned int)Ls[rr][c0 - 1] << 16) : 0.f;
        row[r3][17] = (c0 + 16 < 128) ? __uint_as_float((unsigned int)Ls[rr][c0 + 16] << 16) : 0.f;
        const uint4* rp = (const uint4*)&Ls[rr][c0];
        uint4 p0 = rp[0], p1 = rp[1];
        row[r3][1] = blo(p0.x); row[r3][2] = bhi(p0.x);
        row[r3][3] = blo(p0.y); row[r3][4] = bhi(p0.y);
        row[r3][5] = blo(p0.z); row[r3][6] = bhi(p0.z);
        row[r3][7] = blo(p0.w); row[r3][8] = bhi(p0.w);
        row[r3][9]  = blo(p1.x); row[r3][10] = bhi(p1.x);
        row[r3][11] = blo(p1.y); row[r3][12] = bhi(p1.y);
        row[r3][13] = blo(p1.z); row[r3][14] = bhi(p1.z);
        row[r3][15] = blo(p1.w); row[r3][16] = bhi(p1.w);
    }

    union { unsigned short s[16]; uint4 v[2]; } o;
#pragma unroll
    for (int j = 0; j < 16; j++) {
        float s = 0.f;
#pragma unroll
        for (int r3 = 0; r3 < 3; r3++)
            s += w[r3 * 3 + 0] * row[r3][j] + w[r3 * 3 + 1] * row[r3][j + 1]
               + w[r3 * 3 + 2] * row[r3][j + 2];
        o.s[j] = f2bu(s);
    }
    uint4* op = (uint4*)(out + ((size_t)plane << 14) + ((size_t)(ybase + lr) << 7) + c0);
    op[0] = o.v[0];
    op[1] = o.v[1];
}

// ============ K3: per-row inverse L2 norm (q rows then k rows) ==============
__global__ __launch_bounds__(256) void rownorm(
    const bf16* __restrict__ qkv, float* __restrict__ rn)
{
    int r = blockIdx.x;
    int which = (r >= 1536) ? 1 : 0;
    int rr = r - which * 1536;
    int b = rr / 192, c = rr % 192;
    const bf16* p = qkv + ((size_t)(b * 576 + which * 192 + c) << 14);

    float s = 0.f;
    for (int i = threadIdx.x * 8; i < HW; i += 256 * 8) {
        float v[8];
        load8(p + i, v);
#pragma unroll
        for (int j = 0; j < 8; j++) s += v[j] * v[j];
    }
#pragma unroll
    for (int off = 32; off; off >>= 1) s += __shfl_down(s, off);
    __shared__ float red[4];
    if ((threadIdx.x & 63) == 0) red[threadIdx.x >> 6] = s;
    __syncthreads();
    if (threadIdx.x == 0) {
        float t = red[0] + red[1] + red[2] + red[3];
        rn[r] = 1.0f / fmaxf(sqrtf(t), 1e-12f);
    }
}

// ============ K4: MFMA dots S[bh][c][d] = sum_n q[c][n] k[d][n] =============
// grid (16 K-chunks of 1024, 32 bh); 4 waves, each owns a 256-wide K-range.
__global__ __launch_bounds__(256) void attn_dots(
    const bf16* __restrict__ qkv, float* __restrict__ attn)
{
    const int bh = blockIdx.y, b = bh >> 2, h = bh & 3;
    const int tid = threadIdx.x;
    const int wave = tid >> 6, lane = tid & 63;
    const int n0 = blockIdx.x * 1024 + wave * 256;
    const bf16* q  = qkv + ((size_t)(b * 576 + h * 48) << 14);
    const bf16* kp = qkv + ((size_t)(b * 576 + 192 + h * 48) << 14);

    __shared__ __bf16 S[4][2][48][72];   // 55.3 KB; 144B rows: 2-way only

    const int r16 = lane & 15, quad = lane >> 4;

    f32x4 acc[3][3];
#pragma unroll
    for (int i = 0; i < 3; i++)
#pragma unroll
        for (int j = 0; j < 3; j++) acc[i][j] = (f32x4){0.f, 0.f, 0.f, 0.f};

    for (int t = 0; t < 4; t++) {
        const int nb = n0 + t * 64;
        for (int s = lane; s < 48 * 8; s += 64) {
            int c = s >> 3, seg = (s & 7) * 8;
            *(uint4*)&S[wave][0][c][seg] = *(const uint4*)(q  + ((size_t)c << 14) + nb + seg);
            *(uint4*)&S[wave][1][c][seg] = *(const uint4*)(kp + ((size_t)c << 14) + nb + seg);
        }
        __syncthreads();
#pragma unroll
        for (int half = 0; half < 2; half++) {
            const int kb = half * 32 + quad * 8;
            bf16x8 qa[3], ka[3];
#pragma unroll
            for (int i = 0; i < 3; i++) {
                qa[i] = *(const bf16x8*)&S[wave][0][i * 16 + r16][kb];
                ka[i] = *(const bf16x8*)&S[wave][1][i * 16 + r16][kb];
            }
#pragma unroll
            for (int i = 0; i < 3; i++)
#pragma unroll
                for (int j = 0; j < 3; j++)
                    acc[i][j] = __builtin_amdgcn_mfma_f32_16x16x32_bf16(
                        qa[i], ka[j], acc[i][j], 0, 0, 0);
        }
        __syncthreads();
    }

    float* ap = attn + (size_t)bh * 2304;
#pragma unroll
    for (int i = 0; i < 3; i++)
#pragma unroll
        for (int j = 0; j < 3; j++) {
            int c = i * 16 + quad * 4;
            int d = j * 16 + r16;
#pragma unroll
            for (int r = 0; r < 4; r++)
                atomicAdd(&ap[(c + r) * 48 + d], acc[i][j][r]);
        }
}

// ============ K5: scale by norms & temperature, softmax over d ==============
__global__ __launch_bounds__(64) void softmax48(
    float* __restrict__ attn, const float* __restrict__ rn,
    const float* __restrict__ temp)
{
    int bh = blockIdx.x, b = bh >> 2, h = bh & 3;
    int c = threadIdx.x;
    if (c >= 48) return;
    float t = temp[h];
    float iq = rn[b * 192 + h * 48 + c];
    const float* ik = rn + 1536 + b * 192 + h * 48;
    float* row = attn + (size_t)bh * 2304 + c * 48;

    float v[48];
    float mx = -1e30f;
#pragma unroll
    for (int d = 0; d < 48; d++) {
        v[d] = row[d] * iq * ik[d] * t;
        mx = fmaxf(mx, v[d]);
    }
    float s = 0.f;
#pragma unroll
    for (int d = 0; d < 48; d++) {
        v[d] = expf(v[d] - mx);
        s += v[d];
    }
    float inv = 1.0f / s;
#pragma unroll
    for (int d = 0; d < 48; d++) row[d] = v[d] * inv;
}

// ============ K6: aout[b][n][h*48+c] = sum_d attn[c][d] * v[d][n] ===========
// output written n-major (k-contiguous) so K7 needs no transpose.
__global__ __launch_bounds__(256) void attn_v(
    const float* __restrict__ attn, const bf16* __restrict__ qkv,
    bf16* __restrict__ aout)
{
    int bh = blockIdx.y, b = bh >> 2, h = bh & 3;
    int n = blockIdx.x * 256 + threadIdx.x;

    __shared__ float A[48 * 48];
    for (int i = threadIdx.x; i < 2304; i += 256) A[i] = attn[(size_t)bh * 2304 + i];
    __syncthreads();

    const bf16* v = qkv + ((size_t)(b * 576 + 384 + h * 48) << 14) + n;
    float acc[48];
#pragma unroll
    for (int c = 0; c < 48; c++) acc[c] = 0.f;

    for (int d = 0; d < 48; d++) {
        float vd = b2f(v[(size_t)d << 14]);
#pragma unroll
        for (int c = 0; c < 48; c++) acc[c] += A[c * 48 + d] * vd;
    }
    union { unsigned short s[48]; uint4 v4[6]; } o;
#pragma unroll
    for (int c = 0; c < 48; c++) o.s[c] = f2bu(acc[c]);
    uint4* op = (uint4*)(aout + (((size_t)b << 14) + n) * 192 + h * 48);
#pragma unroll
    for (int j = 0; j < 6; j++) op[j] = o.v4[j];
}

// ============================================================================
extern "C" void kernel_launch(void* const* d_in, const int* in_sizes, int n_in,
                              void* d_out, int out_size, void* d_ws, size_t ws_size,
                              hipStream_t stream)
{
    const float* x      = (const float*)d_in[0];
    const float* qkv_w  = (const float*)d_in[1];
    const float* dw_w   = (const float*)d_in[2];
    const float* proj_w = (const float*)d_in[3];
    const float* temp   = (const float*)d_in[4];
    float* out = (float*)d_out;

    char* ws = (char*)d_ws;
    const size_t Q = (size_t)8 * 576 * HW * sizeof(bf16);     // 151 MB region
    bf16*  qkv0 = (bf16*)ws;          // K1 out (pre-dw qkv), later reused as aout
    bf16*  qkv1 = (bf16*)(ws + Q);    // xT first, then post-dw qkv
    bf16*  xT   = qkv1;               // 8*16384*192 bf16 = 100.7 MB <= Q; dead
                                      // before dwconv overwrites the region
    float* attn = (float*)(ws + 2 * Q);
    float* rn   = (float*)(ws + 2 * Q + (size_t)32 * 2304 * sizeof(float));
    bf16*  aout = qkv0;               // safe: qkv0 consumed by dwconv already

    // 0) transpose + cast: x -> xT [b][n][k]
    transpose_cast<<<dim3(3, 256, 8), 256, 0, stream>>>(x, xT);
    // 1) qkv 1x1 conv: qkv0[b][576][n] = qkv_w @ x  (reads xT)
    gemm_nk<bf16><<<dim3(9, 128, 8), 256, 0, stream>>>(qkv_w, xT, qkv0, 576, HW);
    // 2) depthwise 3x3 (overwrites xT region with qkv1 — xT fully consumed)
    dwconv3x3<<<dim3(8 * 576 * 4), 256, 0, stream>>>(qkv0, dw_w, qkv1);
    // 3) inverse L2 norms for q and k rows
    rownorm<<<dim3(3072), 256, 0, stream>>>(qkv1, rn);
    // 4) attention dots (MFMA, f32 atomics into zeroed buffer)
    hipMemsetAsync(attn, 0, (size_t)32 * 2304 * sizeof(float), stream);
    attn_dots<<<dim3(16, 32), 256, 0, stream>>>(qkv1, attn);
    // 5) scale + softmax
    softmax48<<<dim3(32), 64, 0, stream>>>(attn, rn, temp);
    // 6) attn @ v -> aout [b][n][192] (k-contiguous for K7)
    attn_v<<<dim3(64, 32), 256, 0, stream>>>(attn, qkv1, aout);
    // 7) proj 1x1 conv: out[b][192][n] = proj_w @ aout
    gemm_nk<float><<<dim3(3, 128, 8), 256, 0, stream>>>(proj_w, aout, out, 192, HW);
}